// Round 13
// baseline (114.363 us; speedup 1.0000x reference)
//
#include <hip/hip_runtime.h>

// Chamfer distance — exact, pruned by x-binning (brute-force fallback if
// the workspace can't hold the sorted copies).
//
// R4-R11 (brute): 46.3us floor. pk_fma = 2x scalar (no packed fp32 gain);
// TLP/pipelining null on brute. launch_bounds arg2 = min BLOCKS/CU;
// VGPR cap = 2048/(arg2 x waves_per_block).
// R14: weak stop -> full scan. R15: block stop: 58us (36% scan + big
// overhead). R16: cluster-shuffle + frontier gaps: 48us, conflicts 0,
// true VALU ~9us -> 80% is serial latency: per-tile dependent chain
// (reduce->bm->gap loads->stage->barrier) with only 4 blocks/CU (occ 15%).
// R17 (this): wave-autonomous blocks. GP=16 preds, 64 thr = 1 WAVE,
// grid 4096 = 16 blocks/CU (4x independent chains, finer balance,
// narrower windows). All reduces via shfl_xor. Speculative dbuf staging:
// tile k+1 loads issued (gated by STALE bm — conservative, exact) before
// computing tile k; break check uses fresh bm at the computed frontier.
// Gap-x loads prefetched one tile ahead. TT=256, LDS 8.4KB.
// Predict: main 48 -> 10-18us, bench ~45-65, absmax 0.

#define NBINS 256
#define XLO -6.0f
#define XHI 6.0f

// pruned main kernel
#define TPW 64     // threads = one wave
#define GPP 16     // preds per block
#define TTT 256    // targets per staged tile
#define ROWS 8     // rows per tile (cluster covers all rows)
#define RLEN 32    // targets per row
#define LROW 33    // RLEN + 1 float4 pad -> rows at banks {0,4,..,28}
#define MAXT 68    // 2*M/TTT + 4 : defensive cap

// bin sort
#define BST 1024

// brute-force fallback params (R11, unchanged)
#define THREADS 512
#define P 8
#define G 128
#define TILE 32
#define LSTRIDE (TILE + 1)
#define TSPLIT 2
#define BUFSZ (32 * LSTRIDE)

typedef float float2_t __attribute__((ext_vector_type(2)));
typedef float float4_t __attribute__((ext_vector_type(4)));

// ---------- pass 1: counting sort by x-bin, emit float4 {x,y,z,|q|^2} ----
__global__ __launch_bounds__(BST) void bin_sort_kernel(
    const float* __restrict__ pred, const float* __restrict__ target,
    float4_t* __restrict__ sorted, int* __restrict__ binBase, int M) {
  int bs = blockIdx.x;  // b*2 + side
  int b = bs >> 1, side = bs & 1;
  const float* src = (side ? target : pred) + (size_t)b * M * 3;
  float4_t* out = sorted + (size_t)bs * M;
  int* bases = binBase + bs * (NBINS + 1);

  __shared__ int cnt[NBINS];
  __shared__ int scan[NBINS];
  __shared__ int cur[NBINS];
  int t = threadIdx.x;
  for (int i = t; i < NBINS; i += BST) cnt[i] = 0;
  __syncthreads();
  const float invW = (float)NBINS / (XHI - XLO);
  for (int i = t; i < M; i += BST) {
    float x = src[i * 3];
    int bin = (int)((x - XLO) * invW);
    bin = bin < 0 ? 0 : (bin > NBINS - 1 ? NBINS - 1 : bin);
    atomicAdd(&cnt[bin], 1);
  }
  __syncthreads();
  // parallel inclusive scan (Hillis-Steele) over NBINS=256 counts
  if (t < NBINS) scan[t] = cnt[t];
  __syncthreads();
  for (int off = 1; off < NBINS; off <<= 1) {
    int v = 0;
    if (t < NBINS && t >= off) v = scan[t - off];
    __syncthreads();
    if (t < NBINS) scan[t] += v;
    __syncthreads();
  }
  if (t < NBINS) {
    int excl = scan[t] - cnt[t];
    bases[t] = excl;
    cur[t] = excl;
  }
  if (t == 0) bases[NBINS] = M;
  __syncthreads();
  for (int i = t; i < M; i += BST) {
    float x = src[i * 3], y = src[i * 3 + 1], z = src[i * 3 + 2];
    int bin = (int)((x - XLO) * invW);
    bin = bin < 0 ? 0 : (bin > NBINS - 1 ? NBINS - 1 : bin);
    int pos = atomicAdd(&cur[bin], 1);
    out[pos] = (float4_t){x, y, z, x * x + y * y + z * z};
  }
}

// ---------- pass 2: pruned min scan (single-wave autonomous blocks) -----
__global__ __launch_bounds__(TPW, 16) void chamfer_min_kernel(
    const float4_t* __restrict__ sorted, const int* __restrict__ binBase,
    float* __restrict__ wsmin, int M) {
  const int bpd = M / GPP;  // blocks per (b,dir) = 512
  int bid = blockIdx.x;
  int pblk = bid % bpd;
  int bd = bid / bpd;
  int dir = bd & 1, b = bd >> 1;
  int srcBS = b * 2 + dir;
  int refBS = b * 2 + (dir ^ 1);
  const float4_t* src = sorted + (size_t)srcBS * M;
  const float4_t* ref = sorted + (size_t)refBS * M;
  const int* rbase = binBase + refBS * (NBINS + 1);

  __shared__ float4_t tile[2][ROWS * LROW];  // 8.4 KB double buffer

  int t = threadIdx.x;
  int c = t >> 3;  // cluster 0..7 (8 consecutive lanes)
  int r = t & 7;   // row 0..7 within cluster
  int pbase = pblk * GPP;

  // two preds per thread: c and c+8 (cluster-uniform)
  float4_t v0 = src[pbase + c];
  float4_t v1 = src[pbase + c + 8];
  float ax0 = -2.f * v0.x, ay0 = -2.f * v0.y, az0 = -2.f * v0.z, cm0 = v0.w;
  float ax1 = -2.f * v1.x, ay1 = -2.f * v1.y, az1 = -2.f * v1.z, cm1 = v1.w;
  float mn0 = 3.0e38f, mn1 = 3.0e38f;

  const float W = (XHI - XLO) / (float)NBINS;
  // conservative slab bounds from bin-sortedness (no reduce needed)
  float pxmn = src[pbase].x - W;
  float pxmx = src[pbase + GPP - 1].x + W;

  int cl0 = (int)((pxmn - XLO) * ((float)NBINS / (XHI - XLO)));
  cl0 = cl0 < 0 ? 0 : (cl0 > NBINS - 1 ? NBINS - 1 : cl0);
  int Lpos = rbase[cl0 + 1];  // left unscanned = [0,Lpos)
  int Rpos = Lpos;            // right unscanned = [Rpos,M)

  float4_t st0, st1, st2, st3;  // staged tile (4 float4 / lane)
  int nL, nR, lstart, fill;

#define LDST(k_, reg_)                                              \
  {                                                                 \
    int i_ = t + TPW * (k_);                                        \
    reg_ = (float4_t){0.f, 0.f, 0.f, 3.0e38f};                      \
    if (i_ < fill) {                                                \
      int idx_ = (i_ < nL) ? (lstart + i_) : (Rpos + (i_ - nL));    \
      reg_ = ref[idx_];                                             \
    }                                                               \
  }
#define WRST(k_, reg_, bb_)                                         \
  {                                                                 \
    int i_ = t + TPW * (k_);                                        \
    tile[bb_][(i_ >> 5) * LROW + (i_ & 31)] = reg_;                 \
  }

  // ---- prologue: stage tile 0 into buf 0 ----
  {
    int aL = Lpos, aR = M - Rpos;
    nL = aL < TTT / 2 ? aL : TTT / 2;
    nR = aR < TTT - nL ? aR : TTT - nL;
    nL = aL < TTT - nR ? aL : TTT - nR;
    lstart = Lpos - nL;
    fill = nL + nR;
    LDST(0, st0) LDST(1, st1) LDST(2, st2) LDST(3, st3)
    Lpos = lstart;
    Rpos += nR;
    WRST(0, st0, 0) WRST(1, st1, 0) WRST(2, st2, 0) WRST(3, st3, 0)
  }
  // gap-x prefetch for frontier F1 (uniform address -> broadcast load)
  float gxL = (Lpos > 0) ? ref[Lpos - 1].x : 0.f;
  float gxR = (Rpos < M) ? ref[Rpos].x : 0.f;

  float prevbm = 3.0e38f;
  float f0 = 3.0e38f, f1 = 3.0e38f;
  int cur = 0;
  __syncthreads();  // 1-wave block: LDS visibility fence (cheap)

  for (int it = 0; it < MAXT; ++it) {  // cap: always terminates
    // F_{k+1} (frontier of the region computed after this tile)
    int cL = Lpos, cR = Rpos;
    float gapL = 3.0e38f, gapR = 3.0e38f;
    // bound: unscanned-left x <= gxL + W (bin-sorted); right >= gxR - W
    if (cL > 0) gapL = fmaxf(0.f, pxmn - (gxL + W));
    if (cR < M) gapR = fmaxf(0.f, (gxR - W) - pxmx);
    bool exL = (cL <= 0), exR = (cR >= M);
    // speculative staging of tile k+1, gated by STALE bm (conservative:
    // prevbm >= bm, so a gated-off side is provably done -> exact)
    bool dL = exL || (prevbm <= 0.999f * gapL * gapL);
    bool dR = exR || (prevbm <= 0.999f * gapR * gapR);
    if (!(dL && dR)) {
      int aL = dL ? 0 : Lpos;
      int aR = dR ? 0 : (M - Rpos);
      nL = aL < TTT / 2 ? aL : TTT / 2;
      nR = aR < TTT - nL ? aR : TTT - nL;
      nL = aL < TTT - nR ? aL : TTT - nR;
      lstart = Lpos - nL;
      fill = nL + nR;
      LDST(0, st0) LDST(1, st1) LDST(2, st2) LDST(3, st3)  // in flight
      Lpos = lstart;
      Rpos += nR;
    }

    // ---- compute tile k from buf[cur]: row r, preds c and c+8 ----------
    const float4_t* tp = &tile[cur][r * LROW];
#pragma unroll
    for (int j = 0; j < RLEN; j += 4) {
      float4_t q0 = tp[j + 0];  // 8 distinct rows/wave, banks {0,4..28}
      float4_t q1 = tp[j + 1];
      float4_t q2 = tp[j + 2];
      float4_t q3 = tp[j + 3];
      float d00 = fmaf(ax0, q0.x, fmaf(ay0, q0.y, fmaf(az0, q0.z, q0.w)));
      float d01 = fmaf(ax0, q1.x, fmaf(ay0, q1.y, fmaf(az0, q1.z, q1.w)));
      float d02 = fmaf(ax0, q2.x, fmaf(ay0, q2.y, fmaf(az0, q2.z, q2.w)));
      float d03 = fmaf(ax0, q3.x, fmaf(ay0, q3.y, fmaf(az0, q3.z, q3.w)));
      mn0 = fminf(fminf(mn0, d00), d01);  // v_min3
      mn0 = fminf(fminf(mn0, d02), d03);
      float d10 = fmaf(ax1, q0.x, fmaf(ay1, q0.y, fmaf(az1, q0.z, q0.w)));
      float d11 = fmaf(ax1, q1.x, fmaf(ay1, q1.y, fmaf(az1, q1.z, q1.w)));
      float d12 = fmaf(ax1, q2.x, fmaf(ay1, q2.y, fmaf(az1, q2.z, q2.w)));
      float d13 = fmaf(ax1, q3.x, fmaf(ay1, q3.y, fmaf(az1, q3.z, q3.w)));
      mn1 = fminf(fminf(mn1, d10), d11);
      mn1 = fminf(fminf(mn1, d12), d13);
    }

    // ---- all-shuffle reduce: per-pred min (cluster) then wave max ------
    f0 = mn0;
    f0 = fminf(f0, __shfl_xor(f0, 1, 64));
    f0 = fminf(f0, __shfl_xor(f0, 2, 64));
    f0 = fminf(f0, __shfl_xor(f0, 4, 64));
    f1 = mn1;
    f1 = fminf(f1, __shfl_xor(f1, 1, 64));
    f1 = fminf(f1, __shfl_xor(f1, 2, 64));
    f1 = fminf(f1, __shfl_xor(f1, 4, 64));
    float vv = fmaxf(f0 + cm0, f1 + cm1);
    vv = fmaxf(vv, __shfl_xor(vv, 8, 64));
    vv = fmaxf(vv, __shfl_xor(vv, 16, 64));
    float bm = fmaxf(vv, __shfl_xor(vv, 32, 64));

    // ---- exact stop at F_{k+1} with FRESH bm ---------------------------
    bool fL = exL || (bm <= 0.999f * gapL * gapL);
    bool fR = exR || (bm <= 0.999f * gapR * gapR);
    if (fL && fR) break;  // excluded targets have d^2 >= gap^2 > bm
    prevbm = bm;

    // ---- commit tile k+1 (vmcnt wait auto-inserted before st use) ------
    WRST(0, st0, cur ^ 1) WRST(1, st1, cur ^ 1)
    WRST(2, st2, cur ^ 1) WRST(3, st3, cur ^ 1)
    // gap-x prefetch for F_{k+2}
    gxL = (Lpos > 0) ? ref[Lpos - 1].x : 0.f;
    gxR = (Rpos < M) ? ref[Rpos].x : 0.f;
    cur ^= 1;
    __syncthreads();  // LDS visibility for next compute
  }

  if (r == 0) {  // f0,f1 are cluster-reduced mins over everything scanned
    wsmin[(size_t)srcBS * M + pbase + c] = f0 + cm0;
    wsmin[(size_t)srcBS * M + pbase + c + 8] = f1 + cm1;
  }
#undef LDST
#undef WRST
}

// ---------- pass 3a: sum wsmin (pruned path) ----------------------------
__global__ __launch_bounds__(256) void chamfer_reduce_kernel(
    const float* __restrict__ wsmin, float* __restrict__ out, int npts,
    float scale) {
  int tid = blockIdx.x * blockDim.x + threadIdx.x;
  int stride = gridDim.x * blockDim.x;
  double acc = 0.0;
  for (int p = tid; p < npts; p += stride) acc += (double)wsmin[p];
  for (int off = 32; off > 0; off >>= 1) acc += __shfl_down(acc, off, 64);
  __shared__ double wsum[256 / 64];
  int t = threadIdx.x;
  if ((t & 63) == 0) wsum[t >> 6] = acc;
  __syncthreads();
  if (t == 0) {
    double s = 0.0;
#pragma unroll
    for (int w = 0; w < 256 / 64; ++w) s += wsum[w];
    atomicAdd(out, (float)(s * (double)scale));
  }
}

// =================== fallback: R11 brute force (512KB ws) ===============
__global__ __launch_bounds__(THREADS, 2) void chamfer_brute_kernel(
    const float* __restrict__ pred, const float* __restrict__ target,
    float* __restrict__ wsmin, int M) {
  const int blocksPerDir = M / G;  // 64
  int bid = blockIdx.x;
  int pblk = bid % blocksPerDir;
  int rest = bid / blocksPerDir;
  int ts = rest % TSPLIT;
  int bd = rest / TSPLIT;
  int dir = bd & 1;
  int b = bd >> 1;
  const float* src = (dir ? target : pred) + (size_t)b * M * 3;
  const float* ref = (dir ? pred : target) + (size_t)b * M * 3;

  __shared__ float4_t lds[2 * BUFSZ];

  int t = threadIdx.x;
  int g = t >> 4;
  int l = t & 15;

  float ax[P], ay[P], az[P];
  int pbase = pblk * G;
#pragma unroll
  for (int i = 0; i < P; ++i) {
    int p = pbase + l + 16 * i;
    float x = src[p * 3 + 0], y = src[p * 3 + 1], z = src[p * 3 + 2];
    ax[i] = -2.f * x;
    ay[i] = -2.f * y;
    az[i] = -2.f * z;
  }
  float mn[P];
#pragma unroll
  for (int i = 0; i < P; ++i) mn[i] = 3.0e38f;

  const int spanLen = M / TSPLIT;
  const int tbase = ts * spanLen;
  const int sliceLen = spanLen / 32;   // 128
  const int ntiles = sliceLen / TILE;  // 4

  const int sidx = 2 * t;
  const int ss = sidx >> 5;
  const int sjj = sidx & (TILE - 1);
  const int nb = tbase + ss * sliceLen + sjj;
  float rx0, ry0, rz0, rx1, ry1, rz1;

  {
    int n = nb;
    rx0 = ref[n * 3 + 0]; ry0 = ref[n * 3 + 1]; rz0 = ref[n * 3 + 2];
    rx1 = ref[n * 3 + 3]; ry1 = ref[n * 3 + 4]; rz1 = ref[n * 3 + 5];
    float4_t* dst = lds + ss * LSTRIDE + sjj;
    dst[0] = (float4_t){rx0, ry0, rz0, rx0 * rx0 + ry0 * ry0 + rz0 * rz0};
    dst[1] = (float4_t){rx1, ry1, rz1, rx1 * rx1 + ry1 * ry1 + rz1 * rz1};
  }
  __syncthreads();

  int cur = 0;
  for (int k = 0; k < ntiles; ++k) {
    if (k + 1 < ntiles) {
      int n = nb + (k + 1) * TILE;
      rx0 = ref[n * 3 + 0]; ry0 = ref[n * 3 + 1]; rz0 = ref[n * 3 + 2];
      rx1 = ref[n * 3 + 3]; ry1 = ref[n * 3 + 4]; rz1 = ref[n * 3 + 5];
    }
    const float4_t* tp = lds + cur * BUFSZ + g * LSTRIDE;
#pragma unroll 2
    for (int j = 0; j < TILE; j += 4) {
      float4_t q0 = tp[j + 0];
      float4_t q1 = tp[j + 1];
      float4_t q2 = tp[j + 2];
      float4_t q3 = tp[j + 3];
#pragma unroll
      for (int i = 0; i < P; ++i) {
        float d0 = fmaf(ax[i], q0.x, fmaf(ay[i], q0.y, fmaf(az[i], q0.z, q0.w)));
        float d1 = fmaf(ax[i], q1.x, fmaf(ay[i], q1.y, fmaf(az[i], q1.z, q1.w)));
        float d2 = fmaf(ax[i], q2.x, fmaf(ay[i], q2.y, fmaf(az[i], q2.z, q2.w)));
        float d3 = fmaf(ax[i], q3.x, fmaf(ay[i], q3.y, fmaf(az[i], q3.z, q3.w)));
        mn[i] = fminf(fminf(mn[i], d0), d1);
        mn[i] = fminf(fminf(mn[i], d2), d3);
      }
    }
    if (k + 1 < ntiles) {
      float4_t* dst = lds + (cur ^ 1) * BUFSZ + ss * LSTRIDE + sjj;
      dst[0] = (float4_t){rx0, ry0, rz0, rx0 * rx0 + ry0 * ry0 + rz0 * rz0};
      dst[1] = (float4_t){rx1, ry1, rz1, rx1 * rx1 + ry1 * ry1 + rz1 * rz1};
    }
    __syncthreads();
    cur ^= 1;
  }

  float* lmin = (float*)lds;
#pragma unroll
  for (int i = 0; i < P; ++i) lmin[g * G + (l + 16 * i)] = mn[i];
  __syncthreads();
  if (t < G) {
    float m = 3.0e38f;
#pragma unroll
    for (int s = 0; s < 32; ++s) m = fminf(m, lmin[s * G + t]);
    int p = pbase + t;
    float x = src[p * 3 + 0], y = src[p * 3 + 1], z = src[p * 3 + 2];
    int pid = (b * 2 + dir) * M + p;
    wsmin[(size_t)pid * TSPLIT + ts] = (x * x + y * y + z * z) + m;
  }
}

// ---------- pass 3b: min over TSPLIT + sum (fallback path) --------------
__global__ __launch_bounds__(256) void chamfer_reduce2_kernel(
    const float* __restrict__ wsmin, float* __restrict__ out, int npts,
    float scale) {
  int tid = blockIdx.x * blockDim.x + threadIdx.x;
  int stride = gridDim.x * blockDim.x;
  double acc = 0.0;
  for (int p = tid; p < npts; p += stride) {
    float2_t v = ((const float2_t*)wsmin)[p];
    acc += (double)fminf(v.x, v.y);
  }
  for (int off = 32; off > 0; off >>= 1) acc += __shfl_down(acc, off, 64);
  __shared__ double wsum[256 / 64];
  int t = threadIdx.x;
  if ((t & 63) == 0) wsum[t >> 6] = acc;
  __syncthreads();
  if (t == 0) {
    double s = 0.0;
#pragma unroll
    for (int w = 0; w < 256 / 64; ++w) s += wsum[w];
    atomicAdd(out, (float)(s * (double)scale));
  }
}

extern "C" void kernel_launch(void* const* d_in, const int* in_sizes, int n_in,
                              void* d_out, int out_size, void* d_ws,
                              size_t ws_size, hipStream_t stream) {
  const float* pred = (const float*)d_in[0];
  const float* target = (const float*)d_in[1];
  float* out = (float*)d_out;
  const int B = 4;
  const int M = in_sizes[0] / (B * 3);  // 8192
  float scale = 1.0f / (float)(B * M);

  hipMemsetAsync(out, 0, sizeof(float), stream);  // d_out is poisoned 0xAA

  // pruned layout: wsmin [B*2*M f32] | sorted [B*2*M float4] | binBase
  size_t needWsmin = (size_t)B * 2 * M * 4;           // 256 KB
  size_t needSorted = (size_t)B * 2 * M * 16;         // 1 MB
  size_t needBins = (size_t)B * 2 * (NBINS + 1) * 4;  // ~8 KB
  size_t need = needWsmin + needSorted + needBins;

  if (ws_size >= need) {
    float* wsmin = (float*)d_ws;
    float4_t* sorted = (float4_t*)((char*)d_ws + needWsmin);
    int* binBase = (int*)((char*)sorted + needSorted);
    bin_sort_kernel<<<B * 2, BST, 0, stream>>>(pred, target, sorted, binBase,
                                               M);
    int blocks = B * 2 * (M / GPP);  // 4096
    chamfer_min_kernel<<<blocks, TPW, 0, stream>>>(sorted, binBase, wsmin, M);
    int npts = B * 2 * M;  // 65536
    chamfer_reduce_kernel<<<64, 256, 0, stream>>>(wsmin, out, npts, scale);
  } else {
    // fallback: R11 brute force, 512 KB ws (known-good at 46.4us dispatch)
    float* wsmin = (float*)d_ws;  // B*2*M*TSPLIT floats = 512 KB
    int blocks = B * 2 * (M / G) * TSPLIT;  // 1024
    chamfer_brute_kernel<<<blocks, THREADS, 0, stream>>>(pred, target, wsmin,
                                                         M);
    int npts = B * 2 * M;
    chamfer_reduce2_kernel<<<64, 256, 0, stream>>>(wsmin, out, npts, scale);
  }
}